// Round 1
// baseline (1272.473 us; speedup 1.0000x reference)
//
#include <hip/hip_runtime.h>
#include <hip/hip_bf16.h>
#include <cstdint>

#define N_IMG 4
#define C_CH 32
#define R_RAYS 4096
#define S_SAMP 48
#define M_PTS (R_RAYS * S_SAMP)   // 196608 points per image

// ---------------------------------------------------------------------------
// K0: transpose f32 [NP=12, C=32, H, W] -> bf16 [NP, H, W, C]
// tid enumerates output elements (coalesced 2B writes). H == W == 1<<logW.
// ---------------------------------------------------------------------------
__global__ __launch_bounds__(256) void transpose_to_bf16(
    const float* __restrict__ in, __hip_bfloat16* __restrict__ out, int logW) {
  int tid = blockIdx.x * 256 + threadIdx.x;
  int c  = tid & 31;
  int t2 = tid >> 5;                 // np*H*W + h*W + w
  int Wm = (1 << logW) - 1;
  int w  = t2 & Wm;
  int t3 = t2 >> logW;
  int h  = t3 & Wm;
  int np = t3 >> logW;
  float v = in[(((np << 5) + c) << (2 * logW)) + (h << logW) + w];
  out[tid] = __float2bfloat16(v);
}

// ---------------------------------------------------------------------------
// K1: per-point triplane gather + feature heads.
// Planes are bf16 channel-last, so one (y,x0..x0+1) row pair = 128B contiguous.
// ---------------------------------------------------------------------------
__device__ __forceinline__ void acc8(float* feats, int cb, uint4 u, float w) {
  feats[cb + 0] += w * __uint_as_float(u.x << 16);
  feats[cb + 1] += w * __uint_as_float(u.x & 0xffff0000u);
  feats[cb + 2] += w * __uint_as_float(u.y << 16);
  feats[cb + 3] += w * __uint_as_float(u.y & 0xffff0000u);
  feats[cb + 4] += w * __uint_as_float(u.z << 16);
  feats[cb + 5] += w * __uint_as_float(u.z & 0xffff0000u);
  feats[cb + 6] += w * __uint_as_float(u.w << 16);
  feats[cb + 7] += w * __uint_as_float(u.w & 0xffff0000u);
}

__global__ __launch_bounds__(256) void gather_feats(
    const float* __restrict__ coords,
    const __hip_bfloat16* __restrict__ lo_t,   // [12][256][256][32]
    const __hip_bfloat16* __restrict__ hi_t,   // [12][512][512][32]
    const float* __restrict__ w_sigma,         // [32]
    const float* __restrict__ w_rgb,           // [32][3]
    float4* __restrict__ pts)                  // [N*M] {r,g,b,sigma_raw}
{
  __shared__ float sw[C_CH];
  __shared__ float srgb[3 * C_CH];
  int t = threadIdx.x;
  if (t < C_CH) sw[t] = w_sigma[t];
  if (t < 3 * C_CH) srgb[t] = w_rgb[t];      // layout [c*3 + k]
  __syncthreads();

  int idx = blockIdx.x * 256 + t;            // < N*M exactly
  int n = idx / M_PTS;

  float X = coords[idx * 3 + 0] * 2.f;
  float Y = coords[idx * 3 + 1] * 2.f;
  float Z = coords[idx * 3 + 2] * 2.f;

  float feats[C_CH];
#pragma unroll
  for (int c = 0; c < C_CH; ++c) feats[c] = 0.f;

  // plane permutations: (grid_x, grid_y, grid_z[->depth weight])
  const float gxs[3] = {X, X, Y};
  const float gys[3] = {Y, Z, Z};
  const float gzs[3] = {Z, Y, X};

#pragma unroll
  for (int p = 0; p < 3; ++p) {
    float gx = gxs[p], gy = gys[p], gz = gzs[p];
    float wz = (1.f - 0.5f * fabsf(gz)) * (1.f / 6.f);  // /2 maps /3 planes
#pragma unroll
    for (int lev = 0; lev < 2; ++lev) {
      const int logW = lev ? 9 : 8;
      const int W = 1 << logW;
      const __hip_bfloat16* pl = lev ? hi_t : lo_t;
      float xf = ((gx + 1.f) * (float)W - 1.f) * 0.5f;
      float yf = ((gy + 1.f) * (float)W - 1.f) * 0.5f;
      float x0f = floorf(xf), y0f = floorf(yf);
      float fx = xf - x0f, fy = yf - y0f;
      int x0 = (int)x0f, y0 = (int)y0f;
      // inputs guarantee interior; clamp only as OOB-crash safety
      x0 = min(max(x0, 0), W - 2);
      y0 = min(max(y0, 0), W - 2);
      float w00 = wz * (1.f - fy) * (1.f - fx);
      float w01 = wz * (1.f - fy) * fx;
      float w10 = wz * fy * (1.f - fx);
      float w11 = wz * fy * fx;
      int base = ((((n * 3 + p) << logW) + y0) << logW) + x0;  // element row idx
      const uint4* q0 = reinterpret_cast<const uint4*>(pl + base * 32);
      const uint4* q1 = reinterpret_cast<const uint4*>(pl + (base + W) * 32);
#pragma unroll
      for (int j = 0; j < 4; ++j) {
        acc8(feats, j * 8, q0[j], w00);
        acc8(feats, j * 8, q0[j + 4], w01);
        acc8(feats, j * 8, q1[j], w10);
        acc8(feats, j * 8, q1[j + 4], w11);
      }
    }
  }

  float sig = 0.f, r0 = 0.f, r1 = 0.f, r2 = 0.f;
#pragma unroll
  for (int c = 0; c < C_CH; ++c) {
    float f = feats[c];
    sig += f * sw[c];
    r0 += f * srgb[c * 3 + 0];
    r1 += f * srgb[c * 3 + 1];
    r2 += f * srgb[c * 3 + 2];
  }
  float4 o;
  o.x = 1.f / (1.f + __expf(-r0));
  o.y = 1.f / (1.f + __expf(-r1));
  o.z = 1.f / (1.f + __expf(-r2));
  o.w = sig;                                  // raw density (pre-softplus)
  pts[idx] = o;
}

// ---------------------------------------------------------------------------
// K2: alpha compositing, one thread per ray. Each ray's 48 float4 samples are
// contiguous (768B per thread) -> every cache line consumed by one thread.
// ---------------------------------------------------------------------------
__global__ __launch_bounds__(256) void ray_march_k(
    const float4* __restrict__ pts, const float* __restrict__ depths,
    float* __restrict__ out) {
  int t = blockIdx.x * 256 + threadIdx.x;    // < N*R
  const float4* p = pts + (size_t)t * S_SAMP;
  const float* d = depths + (size_t)t * S_SAMP;

  float4 prev = p[0];
  float dprev = d[0];
  float T = 1.f, accR = 0.f, accG = 0.f, accB = 0.f;
#pragma unroll 4
  for (int i = 1; i < S_SAMP; ++i) {
    float4 cur = p[i];
    float dcur = d[i];
    float delta = dcur - dprev;
    float cr = 0.5f * (prev.x + cur.x);
    float cg = 0.5f * (prev.y + cur.y);
    float cb = 0.5f * (prev.z + cur.z);
    float dm = 0.5f * (prev.w + cur.w) - 1.f;
    float sp = fmaxf(dm, 0.f) + log1pf(__expf(-fabsf(dm)));  // softplus
    float a = 1.f - __expf(-sp * delta);
    float w = a * T;
    accR += w * cr; accG += w * cg; accB += w * cb;
    T *= (1.f - a + 1e-10f);
    prev = cur; dprev = dcur;
  }
  out[t * 3 + 0] = accR;
  out[t * 3 + 1] = accG;
  out[t * 3 + 2] = accB;
}

// ---------------------------------------------------------------------------
extern "C" void kernel_launch(void* const* d_in, const int* in_sizes, int n_in,
                              void* d_out, int out_size, void* d_ws, size_t ws_size,
                              hipStream_t stream) {
  const float* plane_lo = (const float*)d_in[0];  // [4,3,32,256,256]
  const float* plane_hi = (const float*)d_in[1];  // [4,3,32,512,512]
  const float* coords   = (const float*)d_in[2];  // [4,196608,3]
  const float* depths   = (const float*)d_in[3];  // [4,4096,48,1]
  const float* w_sigma  = (const float*)d_in[4];  // [32,1]
  const float* w_rgb    = (const float*)d_in[5];  // [32,3]

  const size_t LO_ELEMS = (size_t)12 * 256 * 256 * 32;   // 25,165,824
  const size_t HI_ELEMS = (size_t)12 * 512 * 512 * 32;   // 100,663,296
  char* ws = (char*)d_ws;
  __hip_bfloat16* lo_t = (__hip_bfloat16*)ws;
  __hip_bfloat16* hi_t = (__hip_bfloat16*)(ws + LO_ELEMS * 2);
  float4* pts = (float4*)(ws + LO_ELEMS * 2 + HI_ELEMS * 2);
  // required ws: 50.3MB + 201.3MB + 12.6MB = ~264.2MB

  transpose_to_bf16<<<(int)(LO_ELEMS / 256), 256, 0, stream>>>(plane_lo, lo_t, 8);
  transpose_to_bf16<<<(int)(HI_ELEMS / 256), 256, 0, stream>>>(plane_hi, hi_t, 9);

  gather_feats<<<(N_IMG * M_PTS) / 256, 256, 0, stream>>>(
      coords, lo_t, hi_t, w_sigma, w_rgb, pts);

  ray_march_k<<<(N_IMG * R_RAYS) / 256, 256, 0, stream>>>(
      pts, depths, (float*)d_out);
}

// Round 2
// 184.026 us; speedup vs baseline: 6.9146x; 6.9146x over previous
//
#include <hip/hip_runtime.h>
#include <hip/hip_bf16.h>
#include <cstdint>

#define N_IMG 4
#define C_CH 32
#define R_RAYS 4096
#define S_SAMP 48
#define M_PTS (R_RAYS * S_SAMP)   // 196608 points per image

__device__ __forceinline__ unsigned short f2bf(float f) {
  __hip_bfloat16 h = __float2bfloat16(f);
  return *reinterpret_cast<unsigned short*>(&h);
}

// ---------------------------------------------------------------------------
// K0: per-texel head projection.
// in:  f32 [NP=12, C=32, H, W] plane features
// out: bf16x4 [NP, H, W, 4] = {f·w_sigma, f·w_rgb0, f·w_rgb1, f·w_rgb2}
// Linear heads commute with bilinear sampling and plane/level averaging,
// so gathering these 4 projections is exact (up to one bf16 rounding).
// ---------------------------------------------------------------------------
__global__ __launch_bounds__(256) void project_planes(
    const float* __restrict__ in, const float* __restrict__ w_sigma,
    const float* __restrict__ w_rgb, uint2* __restrict__ out, int logW) {
  __shared__ float sw[4 * C_CH];  // [c*4 + k], k=0 sigma, 1..3 rgb
  int t = threadIdx.x;
  if (t < C_CH) sw[t * 4] = w_sigma[t];
  if (t < 3 * C_CH) sw[(t / 3) * 4 + 1 + (t % 3)] = w_rgb[t];
  __syncthreads();

  int tid = blockIdx.x * 256 + t;            // texel id: np*H*W + h*W + w
  int hw = tid & ((1 << (2 * logW)) - 1);
  int np = tid >> (2 * logW);
  const float* base = in + ((size_t)np << (5 + 2 * logW)) + hw;
  float a0 = 0.f, a1 = 0.f, a2 = 0.f, a3 = 0.f;
#pragma unroll
  for (int c = 0; c < C_CH; ++c) {          // coalesced: threads stride 1 in hw
    float f = base[(size_t)c << (2 * logW)];
    a0 += f * sw[c * 4 + 0];
    a1 += f * sw[c * 4 + 1];
    a2 += f * sw[c * 4 + 2];
    a3 += f * sw[c * 4 + 3];
  }
  uint2 o;
  o.x = (unsigned)f2bf(a0) | ((unsigned)f2bf(a1) << 16);
  o.y = (unsigned)f2bf(a2) | ((unsigned)f2bf(a3) << 16);
  out[tid] = o;
}

// ---------------------------------------------------------------------------
// K1: per-point triplane gather of the 4 projected values (8B per texel).
// 24 naturally-aligned uint2 loads per point; 31.5MB total footprint.
// ---------------------------------------------------------------------------
__device__ __forceinline__ void upk(uint2 u, float* f) {
  f[0] = __uint_as_float(u.x << 16);
  f[1] = __uint_as_float(u.x & 0xffff0000u);
  f[2] = __uint_as_float(u.y << 16);
  f[3] = __uint_as_float(u.y & 0xffff0000u);
}

__global__ __launch_bounds__(256) void gather_pts(
    const float* __restrict__ coords,
    const uint2* __restrict__ lo_p,   // [12][256][256] texel = 4 bf16
    const uint2* __restrict__ hi_p,   // [12][512][512]
    float4* __restrict__ pts)         // [N*M] {r,g,b,sigma_raw}
{
  int idx = blockIdx.x * 256 + threadIdx.x;   // < N*M exactly
  int n = idx / M_PTS;

  float X = coords[idx * 3 + 0] * 2.f;
  float Y = coords[idx * 3 + 1] * 2.f;
  float Z = coords[idx * 3 + 2] * 2.f;

  float acc0 = 0.f, acc1 = 0.f, acc2 = 0.f, acc3 = 0.f;
  const float gxs[3] = {X, X, Y};
  const float gys[3] = {Y, Z, Z};
  const float gzs[3] = {Z, Y, X};

#pragma unroll
  for (int p = 0; p < 3; ++p) {
    float wz = (1.f - 0.5f * fabsf(gzs[p])) * (1.f / 6.f);  // depth wt, /2 maps /3 planes
#pragma unroll
    for (int lev = 0; lev < 2; ++lev) {
      const int logW = lev ? 9 : 8;
      const int W = 1 << logW;
      const uint2* pl = lev ? hi_p : lo_p;
      float xf = ((gxs[p] + 1.f) * (float)W - 1.f) * 0.5f;
      float yf = ((gys[p] + 1.f) * (float)W - 1.f) * 0.5f;
      float x0f = floorf(xf), y0f = floorf(yf);
      float fx = xf - x0f, fy = yf - y0f;
      int x0 = (int)x0f, y0 = (int)y0f;
      x0 = min(max(x0, 0), W - 2);           // inputs interior; OOB safety only
      y0 = min(max(y0, 0), W - 2);
      int base = ((((n * 3 + p) << logW) + y0) << logW) + x0;
      uint2 t00 = pl[base],     t01 = pl[base + 1];
      uint2 t10 = pl[base + W], t11 = pl[base + W + 1];
      float w00 = wz * (1.f - fy) * (1.f - fx);
      float w01 = wz * (1.f - fy) * fx;
      float w10 = wz * fy * (1.f - fx);
      float w11 = wz * fy * fx;
      float f00[4], f01[4], f10[4], f11[4];
      upk(t00, f00); upk(t01, f01); upk(t10, f10); upk(t11, f11);
      acc0 += w00 * f00[0] + w01 * f01[0] + w10 * f10[0] + w11 * f11[0];
      acc1 += w00 * f00[1] + w01 * f01[1] + w10 * f10[1] + w11 * f11[1];
      acc2 += w00 * f00[2] + w01 * f01[2] + w10 * f10[2] + w11 * f11[2];
      acc3 += w00 * f00[3] + w01 * f01[3] + w10 * f10[3] + w11 * f11[3];
    }
  }

  float4 o;
  o.x = 1.f / (1.f + __expf(-acc1));
  o.y = 1.f / (1.f + __expf(-acc2));
  o.z = 1.f / (1.f + __expf(-acc3));
  o.w = acc0;                                 // raw density (pre-softplus)
  pts[idx] = o;
}

// ---------------------------------------------------------------------------
// K2: alpha compositing, one thread per ray (768B contiguous per thread).
// ---------------------------------------------------------------------------
__global__ __launch_bounds__(256) void ray_march_k(
    const float4* __restrict__ pts, const float* __restrict__ depths,
    float* __restrict__ out) {
  int t = blockIdx.x * 256 + threadIdx.x;    // < N*R
  const float4* p = pts + (size_t)t * S_SAMP;
  const float* d = depths + (size_t)t * S_SAMP;

  float4 prev = p[0];
  float dprev = d[0];
  float T = 1.f, accR = 0.f, accG = 0.f, accB = 0.f;
#pragma unroll 4
  for (int i = 1; i < S_SAMP; ++i) {
    float4 cur = p[i];
    float dcur = d[i];
    float delta = dcur - dprev;
    float cr = 0.5f * (prev.x + cur.x);
    float cg = 0.5f * (prev.y + cur.y);
    float cb = 0.5f * (prev.z + cur.z);
    float dm = 0.5f * (prev.w + cur.w) - 1.f;
    float sp = fmaxf(dm, 0.f) + log1pf(__expf(-fabsf(dm)));  // softplus
    float a = 1.f - __expf(-sp * delta);
    float w = a * T;
    accR += w * cr; accG += w * cg; accB += w * cb;
    T *= (1.f - a + 1e-10f);
    prev = cur; dprev = dcur;
  }
  out[t * 3 + 0] = accR;
  out[t * 3 + 1] = accG;
  out[t * 3 + 2] = accB;
}

// ---------------------------------------------------------------------------
extern "C" void kernel_launch(void* const* d_in, const int* in_sizes, int n_in,
                              void* d_out, int out_size, void* d_ws, size_t ws_size,
                              hipStream_t stream) {
  const float* plane_lo = (const float*)d_in[0];  // [4,3,32,256,256]
  const float* plane_hi = (const float*)d_in[1];  // [4,3,32,512,512]
  const float* coords   = (const float*)d_in[2];  // [4,196608,3]
  const float* depths   = (const float*)d_in[3];  // [4,4096,48,1]
  const float* w_sigma  = (const float*)d_in[4];  // [32,1]
  const float* w_rgb    = (const float*)d_in[5];  // [32,3]

  const size_t LO_TEX = (size_t)12 * 256 * 256;   //   786,432 texels
  const size_t HI_TEX = (size_t)12 * 512 * 512;   // 3,145,728 texels
  char* ws = (char*)d_ws;
  uint2* lo_p = (uint2*)ws;                               //  6.3 MB
  uint2* hi_p = (uint2*)(ws + LO_TEX * 8);                // 25.2 MB
  float4* pts = (float4*)(ws + (LO_TEX + HI_TEX) * 8);    // 12.6 MB

  project_planes<<<(int)(LO_TEX / 256), 256, 0, stream>>>(
      plane_lo, w_sigma, w_rgb, lo_p, 8);
  project_planes<<<(int)(HI_TEX / 256), 256, 0, stream>>>(
      plane_hi, w_sigma, w_rgb, hi_p, 9);

  gather_pts<<<(N_IMG * M_PTS) / 256, 256, 0, stream>>>(
      coords, lo_p, hi_p, pts);

  ray_march_k<<<(N_IMG * R_RAYS) / 256, 256, 0, stream>>>(
      pts, depths, (float*)d_out);
}